// Round 6
// baseline (209.105 us; speedup 1.0000x reference)
//
#include <hip/hip_runtime.h>

#define TT    512
#define WW    257
#define HWSZ  (WW*WW)          // 66049
#define IMG2  (2*HWSZ)         // time stride in `output` (2 channels)
#define PX    65280            // 255 rows * 256 padded cols (interior, col 255 = pad)
#define SCALE 3.5682482323055424f   // DT^-0.5 / gamma(1.5)
#define KD    163.84f               // KAPPA / DX^2
#define TCH   32                    // t-rows per prepass block

typedef short bf16x8 __attribute__((ext_vector_type(8)));
typedef short bf16x4 __attribute__((ext_vector_type(4)));
typedef float f32x4  __attribute__((ext_vector_type(4)));

__device__ __forceinline__ float wf(int j) {
    return sqrtf((float)(j + 1)) - sqrtf((float)j);
}
__device__ __forceinline__ float mcoef(int i, int k) {
    if (i == 0 || k > i) return 0.f;
    if (k == i) return 1.f;
    if (k == 0) return -wf(i - 1);
    int d = i - k;
    return wf(d) - wf(d - 1);
}
__device__ __forceinline__ unsigned short f2b(float f) {
    unsigned u = __float_as_uint(f);
    return (unsigned short)((u + 0x7FFFu + ((u >> 16) & 1u)) >> 16);
}
__device__ __forceinline__ float b2f(unsigned short h) {
    return __uint_as_float(((unsigned)h) << 16);
}

// ---- kernel 1: M as bf16 [512][512]
__global__ __launch_bounds__(256)
void build_m(unsigned short* __restrict__ M) {
    int i = blockIdx.x;
    for (int k = threadIdx.x; k < TT; k += 256)
        M[i * TT + k] = f2b(mcoef(i, k));
}

// ---- kernel 2: prepass v5. block = 32 t x one y, 4 waves.
// Lane-per-pixel: every load is a fully-coalesced dword (64 consecutive floats);
// horizontal neighbors via 2 shfls of Q = a*(h0+h2) + b*h1 (symmetric stencil).
__global__ __launch_bounds__(256, 8)
void prepass(const float* __restrict__ uin, const float* __restrict__ f1p,
             const float* __restrict__ lapk,
             unsigned short* __restrict__ uT, unsigned short* __restrict__ sB)
{
    __shared__ unsigned short uSm[TCH][260];

    const int bid  = blockIdx.x;                       // 4080 = 8 * 510
    const int bid2 = (bid & 7) * 510 + (bid >> 3);     // bijective XCD chunking
    const int y    = 1 + bid2 % 255;
    const int tch  = bid2 / 255;                       // 0..15
    const int t0   = tch * TCH;
    const int tid  = threadIdx.x;
    const int w    = tid >> 6;
    const int l    = tid & 63;

    const float ka = lapk[0];   // corner weight (symmetric kernel)
    const float kb = lapk[1];   // edge weight
    const float kc = lapk[4];   // center weight

    // ---------- phase 1: stencil, lane-per-pixel ----------
    for (int it = 0; it < TCH / 4; ++it) {
        const int tt = 8 * w + it;
        const int t  = t0 + tt;
        const size_t ub = (size_t)t * IMG2 + (size_t)(y - 1) * WW;
        const size_t fb = (size_t)t * HWSZ + (size_t)y * WW;
        const size_t so = (size_t)t * PX   + (size_t)(y - 1) * 256;

        #pragma unroll
        for (int k = 0; k < 5; ++k) {
            const int x0 = (k < 4) ? 62 * k : 193;
            const int x  = x0 + l;                    // 0..256, always in-bounds
            float h0 = uin[ub + x];                   // u[t][y-1][x]
            float h1 = uin[ub + WW + x];              // u[t][y  ][x]
            float h2 = uin[ub + 2 * WW + x];          // u[t][y+1][x]
            float fv = f1p[fb + x];                   // f1[t][y][x]
            float P  = h0 + h2;
            float Q  = fmaf(ka, P, kb * h1);
            float qm = __shfl(Q, l - 1, 64);
            float qp = __shfl(Q, l + 1, 64);
            float lap = qm + qp + fmaf(kb, P, kc * h1);
            float s   = h1 - KD * lap - fv;

            const int p = x - 1;                      // output px column
            // lanes 1..62 produce; final chunk also lane 63 (p==255 pad -> 0)
            bool prod = (l >= 1) && ((k == 4) || (l <= 62));
            if (prod) {
                bool pad = (p == 255);
                sB[so + p]  = pad ? (unsigned short)0 : f2b(s);
                uSm[tt][p]  = pad ? (unsigned short)0 : f2b(h1);
            }
        }
    }

    __syncthreads();

    // ---------- phase 2: transpose tile -> uT ----------
    const int c = tid;                       // pixel column 0..255
    unsigned short col[TCH];
    #pragma unroll
    for (int tt = 0; tt < TCH; ++tt) col[tt] = uSm[tt][c];

    unsigned short* dst = uT + ((size_t)(y - 1) * 256 + c) * TT + t0;
    #pragma unroll
    for (int q = 0; q < TCH / 8; ++q) {
        bf16x8 vq;
        #pragma unroll
        for (int e = 0; e < 8; ++e) vq[e] = (short)col[8 * q + e];
        *(bf16x8*)(dst + 8 * q) = vq;
    }
}

// ---- kernel 3: MFMA GEMM + loss. block = 64 px x all 512 t, 8 balanced waves.
__global__ __launch_bounds__(512)
void mainker(const unsigned short* __restrict__ uT,
             const unsigned short* __restrict__ sB,
             const unsigned short* __restrict__ Mb,
             float* __restrict__ d_out)
{
    __shared__ unsigned short uS[64][512];   // 64 KB, XOR-swizzled 16B segments

    const int tid  = threadIdx.x;
    const int w    = tid >> 6;
    const int lane = tid & 63;
    const int lr   = lane & 15;
    const int lg   = lane >> 4;
    const int px0  = blockIdx.x * 64;

    // stage u tile once: wave w stages rows p = 8w..8w+7 (1 KB each)
    #pragma unroll
    for (int pr = 0; pr < 8; ++pr) {
        int p = 8 * w + pr;
        bf16x8 v = *(const bf16x8*)(uT + (size_t)(px0 + p) * TT + lane * 8);
        *(bf16x8*)(&uS[p][(lane ^ (p & 7)) * 8]) = v;
    }
    __syncthreads();

    float lsum = 0.f;
    #pragma unroll
    for (int half = 0; half < 2; ++half) {
        const int i0   = half ? 480 - 32 * w : 32 * w;
        const int nch  = half ? 16 - w : w + 1;        // k-chunks (balanced: 17 total)
        f32x4 acc[4][2];
        #pragma unroll
        for (int a = 0; a < 4; ++a) { acc[a][0] = (f32x4)0.f; acc[a][1] = (f32x4)0.f; }

        for (int kc = 0; kc < nch * 32; kc += 32) {
            bf16x8 b0 = *(const bf16x8*)(Mb + (size_t)(i0 + lr)      * TT + kc + 8 * lg);
            bf16x8 b1 = *(const bf16x8*)(Mb + (size_t)(i0 + 16 + lr) * TT + kc + 8 * lg);
            const int seg = (((kc >> 3) + lg) ^ (lr & 7)) * 8;
            #pragma unroll
            for (int mi = 0; mi < 4; ++mi) {
                bf16x8 a = *(const bf16x8*)(&uS[16 * mi + lr][seg]);
                acc[mi][0] = __builtin_amdgcn_mfma_f32_16x16x32_bf16(a, b0, acc[mi][0], 0, 0, 0);
                acc[mi][1] = __builtin_amdgcn_mfma_f32_16x16x32_bf16(a, b1, acc[mi][1], 0, 0, 0);
            }
        }
        // epilogue: res = SCALE*acc + s ; one 8-B s load per frag
        #pragma unroll
        for (int mi = 0; mi < 4; ++mi)
            #pragma unroll
            for (int nj = 0; nj < 2; ++nj) {
                int t = i0 + 16 * nj + lr;
                bf16x4 sv = *(const bf16x4*)(sB + (size_t)t * PX + px0 + 16 * mi + 4 * lg);
                f32x4 a = acc[mi][nj];
                #pragma unroll
                for (int r = 0; r < 4; ++r) {
                    float res = SCALE * a[r] + b2f((unsigned short)sv[r]);
                    lsum += res * res;
                }
            }
    }

    // reduce: wave shfl -> (reuse uS) -> one atomic per block
    #pragma unroll
    for (int off = 32; off > 0; off >>= 1)
        lsum += __shfl_down(lsum, off, 64);
    __syncthreads();                         // all waves done reading uS
    float* red = (float*)uS;
    if (lane == 0) red[w] = lsum;
    __syncthreads();
    if (tid == 0) {
        float tot = 0.f;
        #pragma unroll
        for (int q = 0; q < 8; ++q) tot += red[q];
        atomicAdd(d_out, tot * (1.0f / 33292800.0f));
    }
}

extern "C" void kernel_launch(void* const* d_in, const int* in_sizes, int n_in,
                              void* d_out, int out_size, void* d_ws, size_t ws_size,
                              hipStream_t stream)
{
    const float* uin  = (const float*)d_in[0];
    const float* f1   = (const float*)d_in[1];
    const float* lapk = (const float*)d_in[2];
    float* out = (float*)d_out;

    unsigned short* Mb = (unsigned short*)d_ws;                    // 512 KB
    unsigned short* uT = Mb + (size_t)TT * TT;                     // 66.8 MB  [px][t]
    unsigned short* sB = uT + (size_t)PX * TT;                     // 66.8 MB  [t][px]

    hipMemsetAsync(out, 0, sizeof(float), stream);
    build_m<<<dim3(TT), 256, 0, stream>>>(Mb);
    prepass<<<dim3(4080), 256, 0, stream>>>(uin, f1, lapk, uT, sB);
    mainker<<<dim3(PX / 64), 512, 0, stream>>>(uT, sB, Mb, out);
}

// Round 7
// 164.766 us; speedup vs baseline: 1.2691x; 1.2691x over previous
//
#include <hip/hip_runtime.h>

#define TT    512
#define WW    257
#define HWSZ  (WW*WW)          // 66049
#define IMG2  (2*HWSZ)         // time stride in `output` (2 channels)
#define SCALE 3.5682482323055424f   // DT^-0.5 / gamma(1.5)
#define KD    163.84f               // KAPPA / DX^2

typedef short bf16x8 __attribute__((ext_vector_type(8)));
typedef short bf16x4 __attribute__((ext_vector_type(4)));
typedef float f32x4  __attribute__((ext_vector_type(4)));
typedef unsigned int u32x4 __attribute__((ext_vector_type(4)));

__device__ __forceinline__ float wf(int j) {
    return sqrtf((float)(j + 1)) - sqrtf((float)j);
}
__device__ __forceinline__ float mcoef(int i, int k) {
    if (i == 0 || k > i) return 0.f;
    if (k == i) return 1.f;
    if (k == 0) return -wf(i - 1);
    int d = i - k;
    return wf(d) - wf(d - 1);
}
__device__ __forceinline__ unsigned short f2b(float f) {
    unsigned u = __float_as_uint(f);
    return (unsigned short)((u + 0x7FFFu + ((u >> 16) & 1u)) >> 16);
}
__device__ __forceinline__ float b2f(unsigned short h) {
    return __uint_as_float(((unsigned)h) << 16);
}

// ---- kernel 1: M as bf16 [512][512] (L2-resident, read by all blocks)
__global__ __launch_bounds__(256)
void build_m(unsigned short* __restrict__ M) {
    int i = blockIdx.x;
    for (int k = threadIdx.x; k < TT; k += 256)
        M[i * TT + k] = f2b(mcoef(i, k));
}

// ---- fused kernel: stage(stencil+s+u_bf16) -> MFMA -> epilogue, chunked over t.
// grid 1020 = 255 y x 4 x-tiles of 64 px. 512 threads = 8 waves.
// Wave w owns i-tiles [32w,32w+32) and [480-32w,512-32w): 17 k-subs each (balanced).
__global__ __launch_bounds__(512, 4)
void fused(const float* __restrict__ uin, const float* __restrict__ f1p,
           const float* __restrict__ lapk, const unsigned short* __restrict__ Mb,
           float* __restrict__ d_out)
{
    __shared__ unsigned short uS[64][64];   // [px][t-local] bf16, XOR-swizzled 16B segs
    __shared__ unsigned short sS[64][68];   // [t-local][px], pad->68 (8B-aligned rows)
    __shared__ float red[8];

    const int tid  = threadIdx.x;
    const int w    = tid >> 6;
    const int lane = tid & 63;
    const int lr   = lane & 15;
    const int lg   = lane >> 4;

    // bijective XCD chunking over 1020 blocks (q=127, r=4); consecutive wg = consecutive y
    const int bid = blockIdx.x;
    const int xcd = bid & 7, idx = bid >> 3;
    const int wg  = (xcd < 4 ? xcd * 128 : 512 + (xcd - 4) * 127) + idx;
    const int y   = 1 + wg % 255;
    const int c0  = (wg / 255) * 64;        // px-column base (image x = c+1)

    const float ka = lapk[0];   // corner
    const float kb = lapk[1];   // edge
    const float kc = lapk[4];   // center

    f32x4 acc0[4][2], acc1[4][2];
    #pragma unroll
    for (int a = 0; a < 4; ++a) {
        acc0[a][0] = (f32x4)0.f; acc0[a][1] = (f32x4)0.f;
        acc1[a][0] = (f32x4)0.f; acc1[a][1] = (f32x4)0.f;
    }

    const int  xo  = (lane == 0) ? -1 : 64;   // extra-Q column: x=c0 (lane0), x=c0+65 (lane1)
    const bool pad = (c0 + lane) == 255;      // last px column is the zero pad
    const int  i00 = 32 * w;                  // half0 i-tile base
    const int  i01 = 480 - 32 * w;            // half1 i-tile base
    const int  ec0 = w >> 1;                  // chunk where half0 completes
    const int  ec1 = (15 - w) >> 1;           // chunk where half1 completes
    float lsum = 0.f;

    for (int c = 0; c < 8; ++c) {
        // ---------- stage chunk c: wave w handles t = 64c + 8w + rr ----------
        {
            const int tb = 64 * c + 8 * w;
            const float* pu = uin + (size_t)tb * IMG2 + (size_t)(y - 1) * WW + (c0 + 1) + lane;
            const float* pe = uin + (size_t)tb * IMG2 + (size_t)(y - 1) * WW + (c0 + 1) + xo;
            const float* pf = f1p + (size_t)tb * HWSZ + (size_t)y * WW + (c0 + 1) + lane;
            u32x4 up;
            #pragma unroll
            for (int rr = 0; rr < 8; ++rr) {
                const float* qu = pu + (size_t)rr * IMG2;
                const float* qe = pe + (size_t)rr * IMG2;
                float a0 = qu[0], a1 = qu[WW], a2 = qu[2 * WW];
                float e0 = qe[0], e1 = qe[WW], e2 = qe[2 * WW];
                float fv = pf[(size_t)rr * HWSZ];
                float P  = a0 + a2;
                float Q  = fmaf(ka, P, kb * a1);        // column-combined at x=c0+1+lane
                float R  = fmaf(kb, P, kc * a1);        // center-column contribution
                float Qe = fmaf(ka, e0 + e2, kb * e1);  // extra cols (lanes 0,1 meaningful)
                float qm = __shfl(Q, lane - 1, 64);
                float qp = __shfl(Q, lane + 1, 64);
                float q0 = __shfl(Qe, 0, 64);
                float q1 = __shfl(Qe, 1, 64);
                if (lane == 0)  qm = q0;
                if (lane == 63) qp = q1;
                float lap = qm + qp + R;
                float s   = a1 - fmaf(KD, lap, fv);     // u - KD*lap - f1
                unsigned short sb = pad ? (unsigned short)0 : f2b(s);
                unsigned short ub = pad ? (unsigned short)0 : f2b(a1);
                sS[8 * w + rr][lane] = sb;
                if (rr & 1) up[rr >> 1] |= ((unsigned)ub) << 16;
                else        up[rr >> 1]  = (unsigned)ub;
            }
            // one swizzled b128 write: row=px(lane), seg_log=w, phys=w^(lane&7)
            *(u32x4*)&uS[lane][(w ^ (lane & 7)) * 8] = up;
        }
        __syncthreads();

        // ---------- MFMA: k-subs 2c, 2c+1 (32 k each) ----------
        #pragma unroll
        for (int sub = 0; sub < 2; ++sub) {
            const int s_ = 2 * c + sub;
            if (s_ <= w) {                               // half0: k < 32(w+1)
                const unsigned short* mb = Mb + (size_t)(i00 + lr) * TT + 64 * c + 32 * sub + 8 * lg;
                bf16x8 b0 = *(const bf16x8*)mb;
                bf16x8 b1 = *(const bf16x8*)(mb + 16 * TT);
                #pragma unroll
                for (int mi = 0; mi < 4; ++mi) {
                    bf16x8 a = *(const bf16x8*)&uS[16 * mi + lr][((4 * sub + lg) ^ (lr & 7)) * 8];
                    acc0[mi][0] = __builtin_amdgcn_mfma_f32_16x16x32_bf16(a, b0, acc0[mi][0], 0, 0, 0);
                    acc0[mi][1] = __builtin_amdgcn_mfma_f32_16x16x32_bf16(a, b1, acc0[mi][1], 0, 0, 0);
                }
            }
            if (s_ <= 15 - w) {                          // half1: k < 512-32w
                const unsigned short* mb = Mb + (size_t)(i01 + lr) * TT + 64 * c + 32 * sub + 8 * lg;
                bf16x8 b0 = *(const bf16x8*)mb;
                bf16x8 b1 = *(const bf16x8*)(mb + 16 * TT);
                #pragma unroll
                for (int mi = 0; mi < 4; ++mi) {
                    bf16x8 a = *(const bf16x8*)&uS[16 * mi + lr][((4 * sub + lg) ^ (lr & 7)) * 8];
                    acc1[mi][0] = __builtin_amdgcn_mfma_f32_16x16x32_bf16(a, b0, acc1[mi][0], 0, 0, 0);
                    acc1[mi][1] = __builtin_amdgcn_mfma_f32_16x16x32_bf16(a, b1, acc1[mi][1], 0, 0, 0);
                }
            }
        }

        // ---------- epilogues due this chunk (consume sS of chunk c) ----------
        if (c == ec0) {
            const int lbase = (w & 1) * 32;              // local t of i00 within chunk
            #pragma unroll
            for (int mi = 0; mi < 4; ++mi)
                #pragma unroll
                for (int nj = 0; nj < 2; ++nj) {
                    bf16x4 sv = *(const bf16x4*)&sS[lbase + 16 * nj + lr][16 * mi + 4 * lg];
                    #pragma unroll
                    for (int r = 0; r < 4; ++r) {
                        float res = SCALE * acc0[mi][nj][r] + b2f((unsigned short)sv[r]);
                        lsum += res * res;
                    }
                }
        }
        if (c == ec1) {
            const int lbase = ((w + 1) & 1) * 32;        // local t of i01 within chunk
            #pragma unroll
            for (int mi = 0; mi < 4; ++mi)
                #pragma unroll
                for (int nj = 0; nj < 2; ++nj) {
                    bf16x4 sv = *(const bf16x4*)&sS[lbase + 16 * nj + lr][16 * mi + 4 * lg];
                    #pragma unroll
                    for (int r = 0; r < 4; ++r) {
                        float res = SCALE * acc1[mi][nj][r] + b2f((unsigned short)sv[r]);
                        lsum += res * res;
                    }
                }
        }
        __syncthreads();
    }

    // ---------- reduce: wave shfl -> LDS -> one atomic per block ----------
    #pragma unroll
    for (int off = 32; off > 0; off >>= 1)
        lsum += __shfl_down(lsum, off, 64);
    if (lane == 0) red[w] = lsum;
    __syncthreads();
    if (tid == 0) {
        float tot = 0.f;
        #pragma unroll
        for (int q = 0; q < 8; ++q) tot += red[q];
        atomicAdd(d_out, tot * (1.0f / 33292800.0f));
    }
}

extern "C" void kernel_launch(void* const* d_in, const int* in_sizes, int n_in,
                              void* d_out, int out_size, void* d_ws, size_t ws_size,
                              hipStream_t stream)
{
    const float* uin  = (const float*)d_in[0];
    const float* f1   = (const float*)d_in[1];
    const float* lapk = (const float*)d_in[2];
    float* out = (float*)d_out;

    unsigned short* Mb = (unsigned short*)d_ws;   // 512 KB

    hipMemsetAsync(out, 0, sizeof(float), stream);
    build_m<<<dim3(TT), 256, 0, stream>>>(Mb);
    fused<<<dim3(1020), 512, 0, stream>>>(uin, f1, lapk, Mb, out);
}

// Round 8
// 122.462 us; speedup vs baseline: 1.7075x; 1.3455x over previous
//
#include <hip/hip_runtime.h>

#define TT    512
#define WW    257
#define HWSZ  (WW*WW)          // 66049
#define IMG2  (2*HWSZ)         // time stride in `output` (2 channels)
#define SCALE 3.5682482323055424f   // DT^-0.5 / gamma(1.5)
#define KD    163.84f               // KAPPA / DX^2

typedef short bf16x8 __attribute__((ext_vector_type(8)));
typedef short bf16x4 __attribute__((ext_vector_type(4)));
typedef float f32x4  __attribute__((ext_vector_type(4)));
typedef unsigned int u32x4 __attribute__((ext_vector_type(4)));

__device__ __forceinline__ float wf(int j) {
    return sqrtf((float)(j + 1)) - sqrtf((float)j);
}
__device__ __forceinline__ float mcoef(int i, int k) {
    if (i == 0 || k > i) return 0.f;
    if (k == i) return 1.f;
    if (k == 0) return -wf(i - 1);
    int d = i - k;
    return wf(d) - wf(d - 1);
}
__device__ __forceinline__ unsigned short f2b(float f) {
    unsigned u = __float_as_uint(f);
    return (unsigned short)((u + 0x7FFFu + ((u >> 16) & 1u)) >> 16);
}
__device__ __forceinline__ float b2f(unsigned short h) {
    return __uint_as_float(((unsigned)h) << 16);
}

// ---- kernel 1: M as bf16 [512][512] (L2-resident)
__global__ __launch_bounds__(256)
void build_m(unsigned short* __restrict__ M) {
    int i = blockIdx.x;
    for (int k = threadIdx.x; k < TT; k += 256)
        M[i * TT + k] = f2b(mcoef(i, k));
}

// ---- fused: batched-prefetch staging -> MFMA -> epilogue, double-buffered LDS.
// grid 1020 = 255 y x 4 x-tiles of 64 px. 512 threads = 8 waves.
// Wave w owns i-tiles [32w,32w+32) and [480-32w,512-32w): 17 k-subs (balanced).
__global__ __launch_bounds__(512, 2)
void fused(const float* __restrict__ uin, const float* __restrict__ f1p,
           const float* __restrict__ lapk, const unsigned short* __restrict__ Mb,
           float* __restrict__ d_out)
{
    __shared__ unsigned short uS[2][64][64];   // [buf][px][t-local], XOR-swizzled segs
    __shared__ unsigned short sS[2][64][68];   // [buf][t-local][px]
    __shared__ float red[8];

    const int tid  = threadIdx.x;
    const int w    = tid >> 6;
    const int lane = tid & 63;
    const int lr   = lane & 15;
    const int lg   = lane >> 4;

    // bijective XCD chunking over 1020 blocks; consecutive wg = consecutive y
    const int bid = blockIdx.x;
    const int xcd = bid & 7, idx = bid >> 3;
    const int wg  = (xcd < 4 ? xcd * 128 : 512 + (xcd - 4) * 127) + idx;
    const int y   = 1 + wg % 255;
    const int c0  = (wg / 255) * 64;        // px-column base (image x = px+1)

    const float ka = lapk[0];   // corner
    const float kb = lapk[1];   // edge
    const float kc = lapk[4];   // center

    f32x4 acc0[4][2], acc1[4][2];
    #pragma unroll
    for (int a = 0; a < 4; ++a) {
        acc0[a][0] = (f32x4)0.f; acc0[a][1] = (f32x4)0.f;
        acc1[a][0] = (f32x4)0.f; acc1[a][1] = (f32x4)0.f;
    }

    const int  xo  = (lane == 0) ? -1 : 64;   // extra-Q col: x=c0 (lane0) / c0+65 (others)
    const bool pad = (c0 + lane) == 255;      // last px column is the zero pad
    const int  i00 = 32 * w;
    const int  i01 = 480 - 32 * w;
    const int  ec0 = w >> 1;                  // chunk where half0 completes
    const int  ec1 = (15 - w) >> 1;           // chunk where half1 completes
    float lsum = 0.f;

    struct PF { float a0[8], a1[8], a2[8], e0[8], e1[8], e2[8], fv[8]; };
    PF rA, rB;

    // issue all 56 loads of chunk c back-to-back (no use -> no waitcnt between)
    auto LOADR = [&](int c, PF& R) {
        const int tb = 64 * c + 8 * w;
        const float* pu = uin + (size_t)tb * IMG2 + (size_t)(y - 1) * WW + (c0 + 1) + lane;
        const float* pe = uin + (size_t)tb * IMG2 + (size_t)(y - 1) * WW + (c0 + 1) + xo;
        const float* pf = f1p + (size_t)tb * HWSZ + (size_t)y * WW + (c0 + 1) + lane;
        #pragma unroll
        for (int rr = 0; rr < 8; ++rr) {
            const float* qu = pu + (size_t)rr * IMG2;
            const float* qe = pe + (size_t)rr * IMG2;
            R.a0[rr] = qu[0]; R.a1[rr] = qu[WW]; R.a2[rr] = qu[2 * WW];
            R.e0[rr] = qe[0]; R.e1[rr] = qe[WW]; R.e2[rr] = qe[2 * WW];
            R.fv[rr] = pf[(size_t)rr * HWSZ];
        }
    };

    // stencil + pack + LDS stage for chunk c into buffer b
    auto STAGE = [&](PF& R, int b) {
        u32x4 up;
        #pragma unroll
        for (int rr = 0; rr < 8; ++rr) {
            float P  = R.a0[rr] + R.a2[rr];
            float Q  = fmaf(ka, P, kb * R.a1[rr]);
            float Rr = fmaf(kb, P, kc * R.a1[rr]);
            float Qe = fmaf(ka, R.e0[rr] + R.e2[rr], kb * R.e1[rr]);
            float qm = __shfl(Q, lane - 1, 64);
            float qp = __shfl(Q, lane + 1, 64);
            float q0 = __shfl(Qe, 0, 64);
            float q1 = __shfl(Qe, 1, 64);
            if (lane == 0)  qm = q0;
            if (lane == 63) qp = q1;
            float lap = qm + qp + Rr;
            float s   = R.a1[rr] - fmaf(KD, lap, R.fv[rr]);
            unsigned short sb = pad ? (unsigned short)0 : f2b(s);
            unsigned short ub = pad ? (unsigned short)0 : f2b(R.a1[rr]);
            sS[b][8 * w + rr][lane] = sb;
            if (rr & 1) up[rr >> 1] |= ((unsigned)ub) << 16;
            else        up[rr >> 1]  = (unsigned)ub;
        }
        *(u32x4*)&uS[b][lane][(w ^ (lane & 7)) * 8] = up;   // conflict-free b128
    };

    auto EPI = [&](f32x4 (&acc)[4][2], int b, int lbase) {
        #pragma unroll
        for (int mi = 0; mi < 4; ++mi)
            #pragma unroll
            for (int nj = 0; nj < 2; ++nj) {
                bf16x4 sv = *(const bf16x4*)&sS[b][lbase + 16 * nj + lr][16 * mi + 4 * lg];
                #pragma unroll
                for (int r = 0; r < 4; ++r) {
                    float res = SCALE * acc[mi][nj][r] + b2f((unsigned short)sv[r]);
                    lsum += res * res;
                }
            }
    };

    LOADR(0, rA);
    #pragma unroll 2
    for (int c = 0; c < 8; ++c) {
        PF& cur = (c & 1) ? rB : rA;
        PF& nxt = (c & 1) ? rA : rB;
        const int b = c & 1;

        STAGE(cur, b);                 // waits on cur's loads, writes LDS buf b
        if (c < 7) LOADR(c + 1, nxt);  // issue next chunk's 56 loads (drain in bg)
        __syncthreads();               // single barrier per chunk (double-buffered)

        #pragma unroll
        for (int sub = 0; sub < 2; ++sub) {
            const int s_ = 2 * c + sub;
            if (s_ <= w) {                               // half0
                const unsigned short* mb = Mb + (size_t)(i00 + lr) * TT + 64 * c + 32 * sub + 8 * lg;
                bf16x8 b0 = *(const bf16x8*)mb;
                bf16x8 b1 = *(const bf16x8*)(mb + 16 * TT);
                #pragma unroll
                for (int mi = 0; mi < 4; ++mi) {
                    bf16x8 a = *(const bf16x8*)&uS[b][16 * mi + lr][((4 * sub + lg) ^ (lr & 7)) * 8];
                    acc0[mi][0] = __builtin_amdgcn_mfma_f32_16x16x32_bf16(a, b0, acc0[mi][0], 0, 0, 0);
                    acc0[mi][1] = __builtin_amdgcn_mfma_f32_16x16x32_bf16(a, b1, acc0[mi][1], 0, 0, 0);
                }
            }
            if (s_ <= 15 - w) {                          // half1
                const unsigned short* mb = Mb + (size_t)(i01 + lr) * TT + 64 * c + 32 * sub + 8 * lg;
                bf16x8 b0 = *(const bf16x8*)mb;
                bf16x8 b1 = *(const bf16x8*)(mb + 16 * TT);
                #pragma unroll
                for (int mi = 0; mi < 4; ++mi) {
                    bf16x8 a = *(const bf16x8*)&uS[b][16 * mi + lr][((4 * sub + lg) ^ (lr & 7)) * 8];
                    acc1[mi][0] = __builtin_amdgcn_mfma_f32_16x16x32_bf16(a, b0, acc1[mi][0], 0, 0, 0);
                    acc1[mi][1] = __builtin_amdgcn_mfma_f32_16x16x32_bf16(a, b1, acc1[mi][1], 0, 0, 0);
                }
            }
        }

        if (c == ec0) EPI(acc0, b, (w & 1) * 32);
        if (c == ec1) EPI(acc1, b, ((w + 1) & 1) * 32);
    }

    // ---------- reduce: wave shfl -> LDS -> one atomic per block ----------
    #pragma unroll
    for (int off = 32; off > 0; off >>= 1)
        lsum += __shfl_down(lsum, off, 64);
    if (lane == 0) red[w] = lsum;
    __syncthreads();
    if (tid == 0) {
        float tot = 0.f;
        #pragma unroll
        for (int q = 0; q < 8; ++q) tot += red[q];
        atomicAdd(d_out, tot * (1.0f / 33292800.0f));
    }
}

extern "C" void kernel_launch(void* const* d_in, const int* in_sizes, int n_in,
                              void* d_out, int out_size, void* d_ws, size_t ws_size,
                              hipStream_t stream)
{
    const float* uin  = (const float*)d_in[0];
    const float* f1   = (const float*)d_in[1];
    const float* lapk = (const float*)d_in[2];
    float* out = (float*)d_out;

    unsigned short* Mb = (unsigned short*)d_ws;   // 512 KB

    hipMemsetAsync(out, 0, sizeof(float), stream);
    build_m<<<dim3(TT), 256, 0, stream>>>(Mb);
    fused<<<dim3(1020), 512, 0, stream>>>(uin, f1, lapk, Mb, out);
}